// Round 1
// baseline (79270.520 us; speedup 1.0000x reference)
//
#include <hip/hip_runtime.h>
#include <math.h>

#define TT 4096
#define HH 1024
#define GC 7168   // 7*H gate columns
#define KK 33     // emb table rows (K+1)
#define NB 256    // blocks: block b owns output elements j in [4b, 4b+4)
#define NT 448    // 7 waves: wave g handles gate group g

// Device-global scratch (avoids d_ws size assumptions; rewritten every launch)
__device__ float g_P[KK * GC];        // precomputed emb@W[0:H] + b_r per event type
__device__ float g_hd[2 * HH];        // double-buffered h_d exchange
__device__ unsigned int g_cnt[TT];    // per-step arrival counters

// ---------------------------------------------------------------------------
// Setup: P[k][j] = b_r[j] + sum_i emb[k][i] * w_r[i][j]; also zero counters.
// ---------------------------------------------------------------------------
__global__ __launch_bounds__(256) void setup_kernel(const float* __restrict__ w_r,
                                                    const float* __restrict__ b_r,
                                                    const float* __restrict__ emb) {
  const int j = blockIdx.x * 256 + threadIdx.x;  // grid = 28 blocks -> j in [0,7168)
  for (int i = j; i < TT; i += GC) g_cnt[i] = 0u;
  float acc[KK];
  const float bj = b_r[j];
#pragma unroll
  for (int k = 0; k < KK; ++k) acc[k] = bj;
  for (int i = 0; i < HH; ++i) {
    const float w = w_r[(size_t)i * GC + j];   // coalesced across threads
#pragma unroll
    for (int k = 0; k < KK; ++k) acc[k] = fmaf(emb[k * HH + i], w, acc[k]);  // emb: uniform (scalar) loads
  }
#pragma unroll
  for (int k = 0; k < KK; ++k) g_P[k * GC + j] = acc[k];
}

// ---------------------------------------------------------------------------
// Main persistent kernel. One block per 4 hidden elements (all 7 gates local).
// Weights for the h-half live in registers: thread (g, jj, r) holds
// w_r[1024 + 4r + 64k + d][g*1024 + 4b + jj] for k in [0,16), d in [0,4).
// ---------------------------------------------------------------------------
__global__ __launch_bounds__(NT) void ctlstm_kernel(const int* __restrict__ event,
                                                    const float* __restrict__ duration,
                                                    const float* __restrict__ w_r,
                                                    float* __restrict__ out) {
  __shared__ __align__(16) float hd_lds[HH];
  __shared__ float gred[7][4];
  const int tid = threadIdx.x;
  const int b = blockIdx.x;
  const int g = tid >> 6;        // wave id = gate group 0..6
  const int l = tid & 63;
  const int jj = l & 3;          // which of the block's 4 columns in this group
  const int r = l >> 2;          // 16 row-chunks per column
  const int col = g * HH + 4 * b + jj;

  // One-time weight load into VGPRs (64 floats/thread).
  float4 w4[16];
#pragma unroll
  for (int k = 0; k < 16; ++k) {
    const float* wp = w_r + (size_t)(HH + 4 * r + 64 * k) * GC + col;
    w4[k].x = wp[0];
    w4[k].y = wp[GC];
    w4[k].z = wp[2 * (size_t)GC];
    w4[k].w = wp[3 * (size_t)GC];
  }
  for (int i = tid; i < HH; i += NT) hd_lds[i] = 0.f;  // h_d(-1) = 0
  float c_st = 0.f, cb_st = 0.f;                       // state lives in tid<4
  __syncthreads();

  for (int t = 0; t < TT; ++t) {
    // ---- Phase A: matvec h_d @ W  (registers x LDS) ----
    float acc = 0.f;
#pragma unroll
    for (int k = 0; k < 16; ++k) {
      const float4 h4 = *(const float4*)&hd_lds[4 * r + 64 * k];
      acc = fmaf(w4[k].x, h4.x, acc);
      acc = fmaf(w4[k].y, h4.y, acc);
      acc = fmaf(w4[k].z, h4.z, acc);
      acc = fmaf(w4[k].w, h4.w, acc);
    }
    // reduce 16 partials per column (r encoded in lane bits 2..5)
    acc += __shfl_xor(acc, 4);
    acc += __shfl_xor(acc, 8);
    acc += __shfl_xor(acc, 16);
    acc += __shfl_xor(acc, 32);
    if (l < 4) {
      const int ev = event[t];                      // uniform -> scalar load
      gred[g][jj] = acc + g_P[ev * GC + col];       // + event-type contribution (incl. bias)
    }
    __syncthreads();

    // ---- Phase B: state update for this block's 4 elements (gates all local) ----
    if (tid < 4) {
      const float gi = gred[0][tid], gf = gred[1][tid], gz = gred[2][tid];
      const float go = gred[3][tid], gib = gred[4][tid], gfb = gred[5][tid];
      const float gdl = gred[6][tid];
      const float si = 1.f / (1.f + expf(-gi));
      const float sf = 1.f / (1.f + expf(-gf));
      const float tz = tanhf(gz);
      const float so = 1.f / (1.f + expf(-go));
      const float sib = 1.f / (1.f + expf(-gib));
      const float sfb = 1.f / (1.f + expf(-gfb));
      const float sp = fmaxf(gdl, 0.f) + log1pf(expf(-fabsf(gdl)));  // stable softplus
      const float c_n = sf * c_st + si * tz;
      const float cb_n = sfb * cb_st + sib * tz;
      c_st = c_n;
      cb_st = cb_n;
      const float dt = duration[t];
      const float cd = cb_n + (c_n - cb_n) * expf(-sp * dt);
      const int j = 4 * b + tid;
      const size_t o = (size_t)t * HH + j;
      out[o] = so * tanhf(c_n);                       // h_seq
      out[(size_t)TT * HH + o] = c_n;                 // c_seq
      out[2 * (size_t)TT * HH + o] = cb_n;            // c_bar_seq
      out[3 * (size_t)TT * HH + o] = so;              // o_seq
      out[4 * (size_t)TT * HH + o] = sp;              // delta_seq
      g_hd[(t & 1) * HH + j] = so * tanhf(cd);        // carried h_d
    }

    if (t < TT - 1) {
      __syncthreads();
      // ---- Global sync: publish h_d slice, wait for all 256 blocks ----
      if (tid == 0) {
        __threadfence();  // release: push g_hd stores to device scope (cross-XCD)
        __hip_atomic_fetch_add(&g_cnt[t], 1u, __ATOMIC_RELEASE, __HIP_MEMORY_SCOPE_AGENT);
        while (__hip_atomic_load(&g_cnt[t], __ATOMIC_RELAXED, __HIP_MEMORY_SCOPE_AGENT) != NB)
          __builtin_amdgcn_s_sleep(1);
        __threadfence();  // acquire: invalidate stale L1/L2 before reading g_hd
      }
      __syncthreads();
      // ---- Reload full h_d into LDS for next step's matvec ----
      if (tid < HH / 4) {
        const float4 h4 = ((const float4*)&g_hd[(t & 1) * HH])[tid];
        ((float4*)hd_lds)[tid] = h4;
      }
      __syncthreads();
    }
  }
}

extern "C" void kernel_launch(void* const* d_in, const int* in_sizes, int n_in,
                              void* d_out, int out_size, void* d_ws, size_t ws_size,
                              hipStream_t stream) {
  const int* event = (const int*)d_in[0];
  const float* duration = (const float*)d_in[1];
  const float* w_r = (const float*)d_in[2];
  const float* b_r = (const float*)d_in[3];
  const float* emb = (const float*)d_in[4];
  float* out = (float*)d_out;
  setup_kernel<<<GC / 256, 256, 0, stream>>>(w_r, b_r, emb);
  ctlstm_kernel<<<NB, NT, 0, stream>>>(event, duration, w_r, out);
}

// Round 3
// 13924.557 us; speedup vs baseline: 5.6929x; 5.6929x over previous
//
#include <hip/hip_runtime.h>
#include <math.h>

#define TT 4096
#define HH 1024
#define GC 7168   // 7*H gate columns
#define KK 33     // emb table rows (K+1)
#define NB 256    // blocks: block b owns output elements j in [4b, 4b+4)
#define NT 448    // 7 waves: wave g handles gate group g

// Device-global scratch (re-initialized by setup_kernel every launch)
__device__ float g_P[KK * GC];                // precomputed emb@W[0:H] + b_r per event type
__device__ unsigned long long g_hd64[2 * HH]; // stamped h_d: (stamp<<32)|float_bits, double-buffered by parity

// ---------------------------------------------------------------------------
// Setup: P[k][j] = b_r[j] + sum_i emb[k][i] * w_r[i][j]; init stamped buffers.
// ---------------------------------------------------------------------------
__global__ __launch_bounds__(256) void setup_kernel(const float* __restrict__ w_r,
                                                    const float* __restrict__ b_r,
                                                    const float* __restrict__ emb) {
  const int j = blockIdx.x * 256 + threadIdx.x;  // grid = 28 blocks -> j in [0,7168)
  if (j < 2 * HH) g_hd64[j] = 0ULL;  // buffer0: stamp 0 value 0.0f (= h_d(-1)); buffer1: stamp 0
  float acc[KK];
  const float bj = b_r[j];
#pragma unroll
  for (int k = 0; k < KK; ++k) acc[k] = bj;
  for (int i = 0; i < HH; ++i) {
    const float w = w_r[(size_t)i * GC + j];   // coalesced across threads
#pragma unroll
    for (int k = 0; k < KK; ++k) acc[k] = fmaf(emb[k * HH + i], w, acc[k]);  // emb: uniform loads
  }
#pragma unroll
  for (int k = 0; k < KK; ++k) g_P[k * GC + j] = acc[k];
}

// ---------------------------------------------------------------------------
// Main persistent kernel. One block per 4 hidden elements (all 7 gates local).
// Recurrent weights live in registers: thread (g, jj, r) holds
// w_r[1024 + 4r + 64k + d][g*1024 + 4b + jj] for k in [0,16), d in [0,4).
// Cross-block exchange: stamped 64-bit values, published via atomic EXCHANGE
// (RMW executes at the coherence point -> guaranteed cross-XCD visibility),
// consumed via relaxed agent-scope atomic loads (round-1-proven path).
// ---------------------------------------------------------------------------
__global__ __launch_bounds__(NT) void ctlstm_kernel(const int* __restrict__ event,
                                                    const float* __restrict__ duration,
                                                    const float* __restrict__ w_r,
                                                    float* __restrict__ out) {
  __shared__ __align__(16) float hd_lds[HH];
  __shared__ float gred[7][4];   // post-activation gate values
  const int tid = threadIdx.x;
  const int b = blockIdx.x;
  const int g = tid >> 6;        // wave id = gate group 0..6
  const int l = tid & 63;
  const int jj = l & 3;          // which of the block's 4 columns in this group
  const int r = l >> 2;          // 16 row-chunks per column
  const int col = g * HH + 4 * b + jj;

  // One-time weight load into registers (64 floats/thread).
  float4 w4[16];
#pragma unroll
  for (int k = 0; k < 16; ++k) {
    const float* wp = w_r + (size_t)(HH + 4 * r + 64 * k) * GC + col;
    w4[k].x = wp[0];
    w4[k].y = wp[GC];
    w4[k].z = wp[2 * (size_t)GC];
    w4[k].w = wp[3 * (size_t)GC];
  }
  for (int i = tid; i < HH; i += NT) hd_lds[i] = 0.f;  // h_d(-1) = 0
  float c_st = 0.f, cb_st = 0.f;                       // state lives in tid<4
  __syncthreads();

  for (int t = 0; t < TT; ++t) {
    // Issue the event-dependent load early; latency hides under the matvec.
    float pval = 0.f;
    if (l < 4) pval = g_P[event[t] * GC + col];

    // ---- Phase A: matvec h_d @ W  (registers x LDS) ----
    float acc = 0.f;
#pragma unroll
    for (int k = 0; k < 16; ++k) {
      const float4 h4 = *(const float4*)&hd_lds[4 * r + 64 * k];
      acc = fmaf(w4[k].x, h4.x, acc);
      acc = fmaf(w4[k].y, h4.y, acc);
      acc = fmaf(w4[k].z, h4.z, acc);
      acc = fmaf(w4[k].w, h4.w, acc);
    }
    // reduce 16 partials per column (r encoded in lane bits 2..5)
    acc += __shfl_xor(acc, 4);
    acc += __shfl_xor(acc, 8);
    acc += __shfl_xor(acc, 16);
    acc += __shfl_xor(acc, 32);
    if (l < 4) {
      float v = acc + pval;  // pval includes bias
      // Per-gate activation here, in parallel across the 7 gate-waves
      // (wave-uniform branch -> no divergence).
      if (g == 2) v = tanhf(v);                                    // g_z
      else if (g == 6) v = fmaxf(v, 0.f) + log1pf(expf(-fabsf(v))); // softplus(g_dl)
      else v = 1.f / (1.f + expf(-v));                             // sigmoids
      gred[g][jj] = v;
    }
    __syncthreads();  // gred ready; hd_lds free for rewrite

    // ---- Phase B (tid<4): short serial chain + publish ----
    if (tid < 4) {
      const float si = gred[0][tid], sf = gred[1][tid], tz = gred[2][tid];
      const float so = gred[3][tid], sib = gred[4][tid], sfb = gred[5][tid];
      const float sp = gred[6][tid];
      const float c_n = fmaf(sf, c_st, si * tz);
      const float cb_n = fmaf(sfb, cb_st, sib * tz);
      c_st = c_n;
      cb_st = cb_n;
      const float dt = duration[t];
      const float cd = fmaf(c_n - cb_n, expf(-sp * dt), cb_n);
      const int j = 4 * b + tid;
      if (t < TT - 1) {  // publish stamped h_d for step t+1 ASAP (coherence-point RMW)
        const float hdv = so * tanhf(cd);
        const unsigned long long pk =
            ((unsigned long long)(unsigned)(t + 1) << 32) | (unsigned long long)__float_as_uint(hdv);
        (void)__hip_atomic_exchange(&g_hd64[((t + 1) & 1) * HH + j], pk,
                                    __ATOMIC_RELAXED, __HIP_MEMORY_SCOPE_AGENT);
      }
      const size_t o = (size_t)t * HH + j;
      out[o] = so * tanhf(c_n);                       // h_seq
      out[(size_t)TT * HH + o] = c_n;                 // c_seq
      out[2 * (size_t)TT * HH + o] = cb_n;            // c_bar_seq
      out[3 * (size_t)TT * HH + o] = so;              // o_seq
      out[4 * (size_t)TT * HH + o] = sp;              // delta_seq
    }

    // ---- Phase C: poll stamped buffer for step t+1, refill hd_lds ----
    // (threads 4..255 start immediately, overlapping Phase B)
    if (t < TT - 1 && tid < 256) {
      const unsigned int want = (unsigned)(t + 1);
      const unsigned long long* buf = &g_hd64[((t + 1) & 1) * HH];
      bool d0 = false, d1 = false, d2 = false, d3 = false;
      for (;;) {
        if (!d0) {
          const unsigned long long p =
              __hip_atomic_load(&buf[tid], __ATOMIC_RELAXED, __HIP_MEMORY_SCOPE_AGENT);
          if ((unsigned)(p >> 32) == want) { hd_lds[tid] = __uint_as_float((unsigned)p); d0 = true; }
        }
        if (!d1) {
          const unsigned long long p =
              __hip_atomic_load(&buf[tid + 256], __ATOMIC_RELAXED, __HIP_MEMORY_SCOPE_AGENT);
          if ((unsigned)(p >> 32) == want) { hd_lds[tid + 256] = __uint_as_float((unsigned)p); d1 = true; }
        }
        if (!d2) {
          const unsigned long long p =
              __hip_atomic_load(&buf[tid + 512], __ATOMIC_RELAXED, __HIP_MEMORY_SCOPE_AGENT);
          if ((unsigned)(p >> 32) == want) { hd_lds[tid + 512] = __uint_as_float((unsigned)p); d2 = true; }
        }
        if (!d3) {
          const unsigned long long p =
              __hip_atomic_load(&buf[tid + 768], __ATOMIC_RELAXED, __HIP_MEMORY_SCOPE_AGENT);
          if ((unsigned)(p >> 32) == want) { hd_lds[tid + 768] = __uint_as_float((unsigned)p); d3 = true; }
        }
        if (d0 && d1 && d2 && d3) break;
        __builtin_amdgcn_s_sleep(1);
      }
    }
    __syncthreads();  // hd_lds ready for next step
  }
}

extern "C" void kernel_launch(void* const* d_in, const int* in_sizes, int n_in,
                              void* d_out, int out_size, void* d_ws, size_t ws_size,
                              hipStream_t stream) {
  const int* event = (const int*)d_in[0];
  const float* duration = (const float*)d_in[1];
  const float* w_r = (const float*)d_in[2];
  const float* b_r = (const float*)d_in[3];
  const float* emb = (const float*)d_in[4];
  float* out = (float*)d_out;
  setup_kernel<<<GC / 256, 256, 0, stream>>>(w_r, b_r, emb);
  ctlstm_kernel<<<NB, NT, 0, stream>>>(event, duration, w_r, out);
}